// Round 4
// baseline (343.172 us; speedup 1.0000x reference)
//
#include <hip/hip_runtime.h>
#include <math.h>

#define N_NODES 50000
#define E_TRAIN 800000
#define E_POS 200000
#define E_NEG 200000

#define NBUCK 196        // ceil(N_NODES/256) coarse dst-buckets
#define BSTRIDE 5120     // temp slots per bucket (mean 4082, 16 sigma margin)
#define PSTRIDE 6912     // padded csr slots per bucket (raw<=5120 + 256*7 pad, mult of 8)
#define PARTA_BLOCKS 196 // ceil(E_TRAIN/4096)

// ---------------- bf16 helpers ----------------

__device__ inline void split_bf16(float f, short& h, short& l) {
    unsigned u = __float_as_uint(f);
    h = (short)(u >> 16);
    float rem = f - __uint_as_float(u & 0xFFFF0000u);
    l = (short)(__float_as_uint(rem) >> 16);
}

__device__ inline unsigned short f2bf_rne(float f) {
    unsigned u = __float_as_uint(f);
    unsigned r = u + 0x7FFFu + ((u >> 16) & 1u);
    return (unsigned short)(r >> 16);
}

__device__ inline float bf2f(unsigned short h) {
    return __uint_as_float(((unsigned)h) << 16);
}

#define WTOT (128 * 256 + 256 * 128 + 128 * 64)

// ---------------- merged: CSR partition phase A + weight/x prep ----------------

__global__ void partA_prep_kernel(
        const int* __restrict__ src, const int* __restrict__ dst,
        int* __restrict__ gcount, unsigned int* __restrict__ temp, int e,
        const float* __restrict__ W1, short* __restrict__ W1h, short* __restrict__ W1l,
        const float* __restrict__ W2, short* __restrict__ W2h, short* __restrict__ W2l,
        const float* __restrict__ W3, short* __restrict__ W3h, short* __restrict__ W3l,
        const float* __restrict__ x, unsigned short* __restrict__ xb, int n4) {
    __shared__ int hist[NBUCK];
    __shared__ int base[NBUCK];
    __shared__ int lcur[NBUCK];
    int tid = threadIdx.x;
    if (blockIdx.x < PARTA_BLOCKS) {
        for (int i = tid; i < NBUCK; i += 256) hist[i] = 0;
        __syncthreads();
        int start = blockIdx.x * 4096;
        int stop = min(start + 4096, e);
        for (int i = start + tid; i < stop; i += 256)
            atomicAdd(&hist[dst[i] >> 8], 1);
        __syncthreads();
        for (int i = tid; i < NBUCK; i += 256) {
            base[i] = atomicAdd(&gcount[i], hist[i]);
            lcur[i] = 0;
        }
        __syncthreads();
        for (int i = start + tid; i < stop; i += 256) {
            int d = dst[i];
            int b = d >> 8;
            int off = atomicAdd(&lcur[b], 1);
            temp[(size_t)b * BSTRIDE + base[b] + off] = ((unsigned)src[i] << 8) | (unsigned)(d & 255);
        }
    } else {
        int i = (blockIdx.x - PARTA_BLOCKS) * 256 + tid;
        if (i < WTOT) {
            const float* W; short *Wh, *Wl; int K, N;
            if (i < 128 * 256) { W = W1; Wh = W1h; Wl = W1l; K = 128; N = 256; }
            else if (i < 128 * 256 + 256 * 128) { i -= 128 * 256; W = W2; Wh = W2h; Wl = W2l; K = 256; N = 128; }
            else { i -= 128 * 256 + 256 * 128; W = W3; Wh = W3h; Wl = W3l; K = 128; N = 64; }
            int k = i / N, n = i - k * N;
            short h, l;
            split_bf16(W[i], h, l);
            Wh[(size_t)n * K + k] = h;
            Wl[(size_t)n * K + k] = l;
        } else {
            int j = i - WTOT;
            if (j < n4) {
                float4 v = ((const float4*)x)[j];
                ushort4 o;
                o.x = f2bf_rne(v.x); o.y = f2bf_rne(v.y);
                o.z = f2bf_rne(v.z); o.w = f2bf_rne(v.w);
                ((ushort4*)xb)[j] = o;
            }
        }
    }
}

// ---------------- phase B: per-bucket CSR with 8-padded node segments ----------------

__global__ void partB_kernel(const unsigned int* __restrict__ temp,
                             const int* __restrict__ gcount,
                             float* __restrict__ dis, int* __restrict__ offs, int* __restrict__ ends,
                             unsigned short* __restrict__ csr) {
    __shared__ int cnt[256];
    __shared__ int loc[256];
    __shared__ int cursor[256];
    int b = blockIdx.x;
    int t = threadIdx.x;
    int total = gcount[b];
    size_t tbase = (size_t)b * BSTRIDE;
    cnt[t] = 0;
    __syncthreads();
    for (int i = t; i < total; i += 256)
        atomicAdd(&cnt[temp[tbase + i] & 255], 1);
    __syncthreads();
    int c = cnt[t];
    int pc = (c + 7) & ~7;             // padded count (mult of 8)
    loc[t] = pc;
    __syncthreads();
    for (int d = 1; d < 256; d <<= 1) {
        int u = 0;
        if (t >= d) u = loc[t - d];
        __syncthreads();
        if (t >= d) loc[t] += u;
        __syncthreads();
    }
    int excl = loc[t] - pc;
    int node = b * 256 + t;
    int gstart = b * PSTRIDE + excl;   // 8-aligned
    if (node < N_NODES) {
        dis[node] = 1.0f / sqrtf((float)(c + 1));  // +1 self loop
        offs[node] = gstart;
        ends[node] = gstart + pc;
    }
    cursor[t] = gstart;
    __syncthreads();
    for (int i = t; i < total; i += 256) {
        unsigned v = temp[tbase + i];
        int pos = atomicAdd(&cursor[v & 255], 1);
        csr[pos] = (unsigned short)(v >> 8);
    }
    __syncthreads();
    for (int j = c; j < pc; j++)
        csr[gstart + j] = 0xFFFFu;
}

// edge weights: wdis[p] = dis[csr[p]] (fp32); sentinel -> src 0, weight 0.
__global__ void wdis_kernel(unsigned short* __restrict__ csr,
                            const float* __restrict__ dis,
                            float* __restrict__ wdis, int n) {
    int i = blockIdx.x * blockDim.x + threadIdx.x;
    if (i < n) {
        unsigned short s = csr[i];
        if (s == 0xFFFFu) { csr[i] = 0; wdis[i] = 0.f; }
        else wdis[i] = dis[s];
    }
}

typedef short bf16x8 __attribute__((ext_vector_type(8)));
typedef float f32x4 __attribute__((ext_vector_type(4)));

// ---------------- MFMA GEMM: 256 threads (4 waves), 64 rows/block, full BN/wave ----
// Grid-shape fix: 782 blocks (~3/CU co-resident, ~2% tail) vs 391x512t
// (1.53/CU, 24% imbalance). Per-wave work identical to the proven R1 config:
// wave = 16 rows x BN cols, A planes pre-split, B staged to LDS via reg
// round-trip with reg double-buffer.

template<int BN, bool BR, bool OBF>
__global__ __launch_bounds__(256) void gemm_fulln_kernel(
        const short* __restrict__ Ah, const short* __restrict__ Al,
        const short* __restrict__ Bth, const short* __restrict__ Btl,
        const float* __restrict__ bias,
        short* __restrict__ Ch, short* __restrict__ Cl,
        unsigned short* __restrict__ Cb,
        int M, int K) {
    constexpr int NI = BN / 16;
    constexpr int BCH = BN * 4;          // 16B chunks per plane per kstep
    constexpr int BP = BCH / 256;        // chunks per thread (4/2/1)
    constexpr size_t BSZ = (size_t)2 * BN * 40 * 2;
    constexpr size_t TSZ = (size_t)4 * 16 * 68 * 4;
    __shared__ __align__(16) char smem[BSZ > TSZ ? BSZ : TSZ];
    short* Bhi = (short*)smem;
    short* Blo = (short*)(smem + (size_t)BN * 40 * 2);
    float* tr  = (float*)smem;

    int tid = threadIdx.x;
    int lane = tid & 63;
    int wv = tid >> 6;                   // 0..3 = row-group
    int brow = blockIdx.x * 64;
    int m_lane = lane & 15;
    int kgrp = lane >> 4;

    int myrow = brow + wv * 16 + m_lane;
    if (myrow >= M) myrow = M - 1;
    const short* Aph = &Ah[(size_t)myrow * K + kgrp * 8];
    const short* Apl = &Al[(size_t)myrow * K + kgrp * 8];

    f32x4 acc[NI];
    #pragma unroll
    for (int i = 0; i < NI; i++) acc[i] = (f32x4){0.f, 0.f, 0.f, 0.f};

    int4 bhReg[BP], blReg[BP];
    bf16x8 ahN, alN, ahC, alC;

    auto loadB = [&](int k0) {
        #pragma unroll
        for (int p = 0; p < BP; p++) {
            int idx = p * 256 + tid;
            int col = idx >> 2;
            int kc = idx & 3;
            size_t o = (size_t)col * K + k0 + kc * 8;
            bhReg[p] = *(const int4*)&Bth[o];
            blReg[p] = *(const int4*)&Btl[o];
        }
    };
    auto loadA = [&](int k0) {
        ahN = *(const bf16x8*)&Aph[k0];
        alN = *(const bf16x8*)&Apl[k0];
    };

    loadB(0); loadA(0);

    for (int k0 = 0; k0 < K; k0 += 32) {
        ahC = ahN; alC = alN;
        #pragma unroll
        for (int p = 0; p < BP; p++) {
            int idx = p * 256 + tid;
            int col = idx >> 2;
            int kc = idx & 3;
            *(int4*)&Bhi[col * 40 + kc * 8] = bhReg[p];
            *(int4*)&Blo[col * 40 + kc * 8] = blReg[p];
        }
        __syncthreads();

        if (k0 + 32 < K) { loadB(k0 + 32); loadA(k0 + 32); }

        #pragma unroll
        for (int ni = 0; ni < NI; ni++) {
            int boff = (ni * 16 + m_lane) * 40 + kgrp * 8;
            bf16x8 bh = *(const bf16x8*)&Bhi[boff];
            bf16x8 bl = *(const bf16x8*)&Blo[boff];
            acc[ni] = __builtin_amdgcn_mfma_f32_16x16x32_bf16(ahC, bh, acc[ni], 0, 0, 0);
            acc[ni] = __builtin_amdgcn_mfma_f32_16x16x32_bf16(alC, bh, acc[ni], 0, 0, 0);
            acc[ni] = __builtin_amdgcn_mfma_f32_16x16x32_bf16(ahC, bl, acc[ni], 0, 0, 0);
        }
        __syncthreads();
    }

    #pragma unroll
    for (int c = 0; c < NI / 4; c++) {
        #pragma unroll
        for (int q = 0; q < 4; q++) {
            int ni = c * 4 + q;
            float bb = 0.f;
            if (BR) bb = bias[ni * 16 + m_lane];
            #pragma unroll
            for (int reg = 0; reg < 4; reg++) {
                float v = acc[ni][reg];
                if (BR) v = fmaxf(v + bb, 0.f);
                tr[wv * 1088 + (kgrp * 4 + reg) * 68 + q * 16 + m_lane] = v;
            }
        }
        #pragma unroll
        for (int j = 0; j < 4; j++) {
            int r = (lane >> 4) + j * 4;
            int g = lane & 15;
            float4 v = *(const float4*)&tr[wv * 1088 + r * 68 + g * 4];
            int row = brow + wv * 16 + r;
            if (row < M) {
                size_t cbase = (size_t)row * BN + c * 64 + g * 4;
                if (OBF) {
                    ushort4 o;
                    o.x = f2bf_rne(v.x); o.y = f2bf_rne(v.y);
                    o.z = f2bf_rne(v.z); o.w = f2bf_rne(v.w);
                    *(ushort4*)&Cb[cbase] = o;
                } else {
                    short4 oh, ol;
                    short h, l;
                    split_bf16(v.x, h, l); oh.x = h; ol.x = l;
                    split_bf16(v.y, h, l); oh.y = h; ol.y = l;
                    split_bf16(v.z, h, l); oh.z = h; ol.z = l;
                    split_bf16(v.w, h, l); oh.w = h; ol.w = l;
                    *(short4*)&Ch[cbase] = oh;
                    *(short4*)&Cl[cbase] = ol;
                }
            }
        }
        __syncthreads();
    }
}

// ---------------- aggregation: bf16 table, 8-padded CSR, precomputed edge weights ----

#define AGG_WAVES 12800
#define AGG_BLOCKS (AGG_WAVES / 4)

template<int F, bool RELU, bool BIAS, int OUTM>
__global__ void aggregate_bf16_kernel(const unsigned short* __restrict__ xb,
                                      short* __restrict__ outh,
                                      short* __restrict__ outl,
                                      float* __restrict__ outf,
                                      const float* __restrict__ dis,
                                      const int* __restrict__ starts,
                                      const int* __restrict__ ends,
                                      const unsigned short* __restrict__ csr_src,
                                      const float* __restrict__ wdis,
                                      const float* __restrict__ bias,
                                      int n) {
    int wid = (blockIdx.x * blockDim.x + threadIdx.x) >> 6;
    int lane = threadIdx.x & 63;
    constexpr int VPT = F / 64;

    for (int v = wid; v < n; v += AGG_WAVES) {
        float dv = dis[v];
        float acc[VPT];
        if constexpr (VPT == 2) {
            ushort2 sv = *(const ushort2*)&xb[(size_t)v * F + lane * 2];
            acc[0] = bf2f(sv.x) * dv;
            acc[1] = bf2f(sv.y) * dv;
        } else {
            acc[0] = bf2f(xb[(size_t)v * F + lane]) * dv;
        }
        int s = __builtin_amdgcn_readfirstlane(starts[v]);
        int e = __builtin_amdgcn_readfirstlane(ends[v]);
        for (int p = s; p < e; p += 8) {
            int4 c0 = *(const int4*)&csr_src[p];
            float4 w0 = *(const float4*)&wdis[p];
            float4 w1 = *(const float4*)&wdis[p + 4];
            int u[8];
            u[0] = (unsigned)c0.x & 0xFFFF; u[1] = (unsigned)c0.x >> 16;
            u[2] = (unsigned)c0.y & 0xFFFF; u[3] = (unsigned)c0.y >> 16;
            u[4] = (unsigned)c0.z & 0xFFFF; u[5] = (unsigned)c0.z >> 16;
            u[6] = (unsigned)c0.w & 0xFFFF; u[7] = (unsigned)c0.w >> 16;
            float w[8];
            w[0] = w0.x; w[1] = w0.y; w[2] = w0.z; w[3] = w0.w;
            w[4] = w1.x; w[5] = w1.y; w[6] = w1.z; w[7] = w1.w;
            if constexpr (VPT == 2) {
                ushort2 g[8];
                #pragma unroll
                for (int q = 0; q < 8; q++)
                    g[q] = *(const ushort2*)&xb[(size_t)u[q] * F + lane * 2];
                #pragma unroll
                for (int q = 0; q < 8; q++) {
                    acc[0] += bf2f(g[q].x) * w[q];
                    acc[1] += bf2f(g[q].y) * w[q];
                }
            } else {
                unsigned short g[8];
                #pragma unroll
                for (int q = 0; q < 8; q++)
                    g[q] = xb[(size_t)u[q] * F + lane];
                #pragma unroll
                for (int q = 0; q < 8; q++) acc[0] += bf2f(g[q]) * w[q];
            }
        }
        size_t base = (size_t)v * F + lane * VPT;
        if constexpr (OUTM == 1) {
            #pragma unroll
            for (int i = 0; i < VPT; i++) {
                float r = acc[i] * dv;
                if (BIAS) r += bias[lane * VPT + i];
                if (RELU) r = fmaxf(r, 0.f);
                outf[base + i] = r;
            }
        } else {
            if constexpr (VPT == 2) {
                float r0 = acc[0] * dv, r1 = acc[1] * dv;
                if (BIAS) { r0 += bias[lane * 2]; r1 += bias[lane * 2 + 1]; }
                if (RELU) { r0 = fmaxf(r0, 0.f); r1 = fmaxf(r1, 0.f); }
                short h0, l0, h1, l1;
                split_bf16(r0, h0, l0);
                split_bf16(r1, h1, l1);
                short2 oh; oh.x = h0; oh.y = h1;
                short2 ol; ol.x = l0; ol.y = l1;
                *(short2*)&outh[base] = oh;
                *(short2*)&outl[base] = ol;
            } else {
                float r = acc[0] * dv;
                if (BIAS) r += bias[lane];
                if (RELU) r = fmaxf(r, 0.f);
                short h, l;
                split_bf16(r, h, l);
                outh[base] = h;
                outl[base] = l;
            }
        }
    }
}

// ---------------- edge dot products: 16 lanes per edge, 4 edges per wave ----------------

__global__ void dot_kernel(const float* __restrict__ h,
                           const int* __restrict__ pos, const int* __restrict__ neg,
                           float* __restrict__ out) {
    int gw = (blockIdx.x * blockDim.x + threadIdx.x) >> 6;
    int lane = threadIdx.x & 63;
    int sub = lane >> 4;
    int pl = lane & 15;
    int e = gw * 4 + sub;
    if (e >= E_POS + E_NEG) return;
    int i0, i1;
    if (e < E_POS) { i0 = pos[e]; i1 = pos[E_POS + e]; }
    else { int t = e - E_POS; i0 = neg[t]; i1 = neg[E_NEG + t]; }
    float4 a = *(const float4*)&h[(size_t)i0 * 64 + pl * 4];
    float4 b = *(const float4*)&h[(size_t)i1 * 64 + pl * 4];
    float v = a.x * b.x + a.y * b.y + a.z * b.z + a.w * b.w;
    v += __shfl_xor(v, 1, 64);
    v += __shfl_xor(v, 2, 64);
    v += __shfl_xor(v, 4, 64);
    v += __shfl_xor(v, 8, 64);
    if (pl == 0) out[e] = v;
}

// ---------------- launch ----------------

extern "C" void kernel_launch(void* const* d_in, const int* in_sizes, int n_in,
                              void* d_out, int out_size, void* d_ws, size_t ws_size,
                              hipStream_t stream) {
    const float* x  = (const float*)d_in[0];
    const int* tei  = (const int*)d_in[1];
    const int* pos  = (const int*)d_in[2];
    const int* neg  = (const int*)d_in[3];
    const float* W1 = (const float*)d_in[4];
    const float* b1 = (const float*)d_in[5];
    const float* W2 = (const float*)d_in[6];
    const float* b2 = (const float*)d_in[7];
    const float* W3 = (const float*)d_in[8];
    const float* b3 = (const float*)d_in[9];
    float* out = (float*)d_out;

    const int* src = tei;
    const int* dst = tei + E_TRAIN;

    char* ws = (char*)d_ws;
    size_t off = 0;
    auto alloc = [&](size_t bytes) -> void* {
        void* p = ws + off;
        off = (off + bytes + 255) & ~(size_t)255;
        return p;
    };
    unsigned short* xb = (unsigned short*)alloc((size_t)N_NODES * 128 * 2);
    short* aggXh       = (short*)alloc((size_t)N_NODES * 128 * 2);
    short* aggXl       = (short*)alloc((size_t)N_NODES * 128 * 2);
    short* h1h         = (short*)alloc((size_t)N_NODES * 256 * 2);
    short* h1l         = (short*)alloc((size_t)N_NODES * 256 * 2);
    unsigned short* xw2b = (unsigned short*)alloc((size_t)N_NODES * 128 * 2);
    short* h2h         = (short*)alloc((size_t)N_NODES * 128 * 2);
    short* h2l         = (short*)alloc((size_t)N_NODES * 128 * 2);
    unsigned short* xw3b = (unsigned short*)alloc((size_t)N_NODES * 64 * 2);
    float* h3          = (float*)alloc((size_t)N_NODES * 64 * 4);
    float* dis  = (float*)alloc(N_NODES * 4);
    int* offs   = (int*)alloc(N_NODES * 4);
    int* ends   = (int*)alloc(N_NODES * 4);
    int* gcount = (int*)alloc(NBUCK * 4);
    unsigned int* temp  = (unsigned int*)alloc((size_t)NBUCK * BSTRIDE * 4);
    unsigned short* csr = (unsigned short*)alloc((size_t)NBUCK * PSTRIDE * 2);
    float* wdis         = (float*)alloc((size_t)NBUCK * PSTRIDE * 4);
    short* Wt1h = (short*)alloc((size_t)128 * 256 * 2);
    short* Wt1l = (short*)alloc((size_t)128 * 256 * 2);
    short* Wt2h = (short*)alloc((size_t)256 * 128 * 2);
    short* Wt2l = (short*)alloc((size_t)256 * 128 * 2);
    short* Wt3h = (short*)alloc((size_t)128 * 64 * 2);
    short* Wt3l = (short*)alloc((size_t)128 * 64 * 2);
    (void)ws_size; (void)n_in; (void)in_sizes; (void)out_size;

    const int n4 = N_NODES * 128 / 4;

    // CSR build + prep (fused): memset + partA/prep + partB + wdis
    hipMemsetAsync(gcount, 0, NBUCK * 4, stream);
    {
        int prep_blocks = (WTOT + n4 + 255) / 256;
        partA_prep_kernel<<<PARTA_BLOCKS + prep_blocks, 256, 0, stream>>>(
            src, dst, gcount, temp, E_TRAIN,
            W1, Wt1h, Wt1l, W2, Wt2h, Wt2l, W3, Wt3h, Wt3l, x, xb, n4);
    }
    partB_kernel<<<NBUCK, 256, 0, stream>>>(temp, gcount, dis, offs, ends, csr);
    {
        int ncsr = NBUCK * PSTRIDE;
        wdis_kernel<<<(ncsr + 255) / 256, 256, 0, stream>>>(csr, dis, wdis, ncsr);
    }

    const int GB = (N_NODES + 63) / 64;   // 782 blocks, 64 rows each

    // layer 1 (agg-first): aggX = agg(xb) [split planes]; h1 = relu(aggX @ W1 + b1)
    aggregate_bf16_kernel<128, false, false, 0><<<AGG_BLOCKS, 256, 0, stream>>>(
        xb, aggXh, aggXl, nullptr, dis, offs, ends, csr, wdis, nullptr, N_NODES);
    gemm_fulln_kernel<256, true, false><<<GB, 256, 0, stream>>>(
        aggXh, aggXl, Wt1h, Wt1l, b1, h1h, h1l, nullptr, N_NODES, 128);

    // layer 2 (gemm-first): xw2 = h1 @ W2 (bf16 out); h2 = relu(agg + b2)
    gemm_fulln_kernel<128, false, true><<<GB, 256, 0, stream>>>(
        h1h, h1l, Wt2h, Wt2l, nullptr, nullptr, nullptr, xw2b, N_NODES, 256);
    aggregate_bf16_kernel<128, true, true, 0><<<AGG_BLOCKS, 256, 0, stream>>>(
        xw2b, h2h, h2l, nullptr, dis, offs, ends, csr, wdis, b2, N_NODES);

    // layer 3 (gemm-first): xw3 = h2 @ W3 (bf16 out); h3 = agg + b3 (fp32)
    gemm_fulln_kernel<64, false, true><<<GB, 256, 0, stream>>>(
        h2h, h2l, Wt3h, Wt3l, nullptr, nullptr, nullptr, xw3b, N_NODES, 128);
    aggregate_bf16_kernel<64, false, true, 1><<<AGG_BLOCKS, 256, 0, stream>>>(
        xw3b, nullptr, nullptr, h3, dis, offs, ends, csr, wdis, b3, N_NODES);

    // edge dots over h3 (64 features, fp32): 4 edges per wave
    const int DOT_WAVES = (E_POS + E_NEG + 3) / 4;
    dot_kernel<<<(DOT_WAVES + 3) / 4, 256, 0, stream>>>(h3, pos, neg, out);
}

// Round 5
// 306.090 us; speedup vs baseline: 1.1211x; 1.1211x over previous
//
#include <hip/hip_runtime.h>
#include <math.h>

#define N_NODES 50000
#define E_TRAIN 800000
#define E_POS 200000
#define E_NEG 200000

#define NBUCK 196        // ceil(N_NODES/256) coarse dst-buckets
#define BSTRIDE 5120     // temp slots per bucket (mean 4082, 16 sigma margin)
#define PSTRIDE 6912     // padded csr slots per bucket (raw<=5120 + 256*7 pad, mult of 8)
#define PARTA_BLOCKS 196 // ceil(E_TRAIN/4096)

// ---------------- bf16 helpers ----------------

__device__ inline void split_bf16(float f, short& h, short& l) {
    unsigned u = __float_as_uint(f);
    h = (short)(u >> 16);
    float rem = f - __uint_as_float(u & 0xFFFF0000u);
    l = (short)(__float_as_uint(rem) >> 16);
}

__device__ inline unsigned short f2bf_rne(float f) {
    unsigned u = __float_as_uint(f);
    unsigned r = u + 0x7FFFu + ((u >> 16) & 1u);
    return (unsigned short)(r >> 16);
}

__device__ inline float bf2f(unsigned short h) {
    return __uint_as_float(((unsigned)h) << 16);
}

#define WTOT (128 * 256 + 256 * 128 + 128 * 64)

// ---------------- merged: CSR partition phase A + weight/x prep ----------------

__global__ void partA_prep_kernel(
        const int* __restrict__ src, const int* __restrict__ dst,
        int* __restrict__ gcount, unsigned int* __restrict__ temp, int e,
        const float* __restrict__ W1, short* __restrict__ W1h, short* __restrict__ W1l,
        const float* __restrict__ W2, short* __restrict__ W2h, short* __restrict__ W2l,
        const float* __restrict__ W3, short* __restrict__ W3h, short* __restrict__ W3l,
        const float* __restrict__ x, unsigned short* __restrict__ xb, int n4) {
    __shared__ int hist[NBUCK];
    __shared__ int base[NBUCK];
    __shared__ int lcur[NBUCK];
    int tid = threadIdx.x;
    if (blockIdx.x < PARTA_BLOCKS) {
        for (int i = tid; i < NBUCK; i += 256) hist[i] = 0;
        __syncthreads();
        int start = blockIdx.x * 4096;
        int stop = min(start + 4096, e);
        for (int i = start + tid; i < stop; i += 256)
            atomicAdd(&hist[dst[i] >> 8], 1);
        __syncthreads();
        for (int i = tid; i < NBUCK; i += 256) {
            base[i] = atomicAdd(&gcount[i], hist[i]);
            lcur[i] = 0;
        }
        __syncthreads();
        for (int i = start + tid; i < stop; i += 256) {
            int d = dst[i];
            int b = d >> 8;
            int off = atomicAdd(&lcur[b], 1);
            temp[(size_t)b * BSTRIDE + base[b] + off] = ((unsigned)src[i] << 8) | (unsigned)(d & 255);
        }
    } else {
        int i = (blockIdx.x - PARTA_BLOCKS) * 256 + tid;
        if (i < WTOT) {
            const float* W; short *Wh, *Wl; int K, N;
            if (i < 128 * 256) { W = W1; Wh = W1h; Wl = W1l; K = 128; N = 256; }
            else if (i < 128 * 256 + 256 * 128) { i -= 128 * 256; W = W2; Wh = W2h; Wl = W2l; K = 256; N = 128; }
            else { i -= 128 * 256 + 256 * 128; W = W3; Wh = W3h; Wl = W3l; K = 128; N = 64; }
            int k = i / N, n = i - k * N;
            short h, l;
            split_bf16(W[i], h, l);
            Wh[(size_t)n * K + k] = h;
            Wl[(size_t)n * K + k] = l;
        } else {
            int j = i - WTOT;
            if (j < n4) {
                float4 v = ((const float4*)x)[j];
                ushort4 o;
                o.x = f2bf_rne(v.x); o.y = f2bf_rne(v.y);
                o.z = f2bf_rne(v.z); o.w = f2bf_rne(v.w);
                ((ushort4*)xb)[j] = o;
            }
        }
    }
}

// ---------------- phase B: per-bucket CSR with 8-padded node segments ----------------

__global__ void partB_kernel(const unsigned int* __restrict__ temp,
                             const int* __restrict__ gcount,
                             float* __restrict__ dis, int* __restrict__ offs, int* __restrict__ ends,
                             unsigned short* __restrict__ csr) {
    __shared__ int cnt[256];
    __shared__ int loc[256];
    __shared__ int cursor[256];
    int b = blockIdx.x;
    int t = threadIdx.x;
    int total = gcount[b];
    size_t tbase = (size_t)b * BSTRIDE;
    cnt[t] = 0;
    __syncthreads();
    for (int i = t; i < total; i += 256)
        atomicAdd(&cnt[temp[tbase + i] & 255], 1);
    __syncthreads();
    int c = cnt[t];
    int pc = (c + 7) & ~7;             // padded count (mult of 8)
    loc[t] = pc;
    __syncthreads();
    for (int d = 1; d < 256; d <<= 1) {
        int u = 0;
        if (t >= d) u = loc[t - d];
        __syncthreads();
        if (t >= d) loc[t] += u;
        __syncthreads();
    }
    int excl = loc[t] - pc;
    int node = b * 256 + t;
    int gstart = b * PSTRIDE + excl;   // 8-aligned
    if (node < N_NODES) {
        dis[node] = 1.0f / sqrtf((float)(c + 1));  // +1 self loop
        offs[node] = gstart;
        ends[node] = gstart + pc;
    }
    cursor[t] = gstart;
    __syncthreads();
    for (int i = t; i < total; i += 256) {
        unsigned v = temp[tbase + i];
        int pos = atomicAdd(&cursor[v & 255], 1);
        csr[pos] = (unsigned short)(v >> 8);
    }
    __syncthreads();
    for (int j = c; j < pc; j++)
        csr[gstart + j] = 0xFFFFu;
}

// edge weights: wdis[p] = dis[csr[p]] (fp32); sentinel -> src 0, weight 0.
__global__ void wdis_kernel(unsigned short* __restrict__ csr,
                            const float* __restrict__ dis,
                            float* __restrict__ wdis, int n) {
    int i = blockIdx.x * blockDim.x + threadIdx.x;
    if (i < n) {
        unsigned short s = csr[i];
        if (s == 0xFFFFu) { csr[i] = 0; wdis[i] = 0.f; }
        else wdis[i] = dis[s];
    }
}

typedef short bf16x8 __attribute__((ext_vector_type(8)));
typedef float f32x4 __attribute__((ext_vector_type(4)));

// ---------------- MFMA GEMM: 512 threads, 128 rows x full BN (R1 shape, proven) ----
// KT is compile-time K. For KT=128 the whole per-wave A stream (4 slices,
// 128 B/thread) is preloaded before the k-loop: all A HBM latency is paid
// once, overlapped; the k-loop body has zero global A-loads. KT=256 keeps
// rolling depth-2. Math bit-identical to R1.

template<int KT, int BN, bool BR, bool OBF>
__global__ __launch_bounds__(512) void gemm_fulln_kernel(
        const short* __restrict__ Ah, const short* __restrict__ Al,
        const short* __restrict__ Bth, const short* __restrict__ Btl,
        const float* __restrict__ bias,
        short* __restrict__ Ch, short* __restrict__ Cl,
        unsigned short* __restrict__ Cb,
        int M) {
    constexpr int NI = BN / 16;
    constexpr int KSTEPS = KT / 32;
    constexpr int BCH = BN * 4;
    constexpr int BP = (BCH + 511) / 512;
    constexpr size_t BSZ = (size_t)2 * BN * 40 * 2;
    constexpr size_t TSZ = (size_t)8 * 16 * 68 * 4;
    __shared__ __align__(16) char smem[BSZ > TSZ ? BSZ : TSZ];
    short* Bhi = (short*)smem;
    short* Blo = (short*)(smem + (size_t)BN * 40 * 2);
    float* tr  = (float*)smem;

    int tid = threadIdx.x;
    int lane = tid & 63;
    int wv = tid >> 6;
    int brow = blockIdx.x * 128;
    int m_lane = lane & 15;
    int kgrp = lane >> 4;

    int myrow = brow + wv * 16 + m_lane;
    if (myrow >= M) myrow = M - 1;
    const short* Aph = &Ah[(size_t)myrow * KT + kgrp * 8];
    const short* Apl = &Al[(size_t)myrow * KT + kgrp * 8];

    f32x4 acc[NI];
    #pragma unroll
    for (int i = 0; i < NI; i++) acc[i] = (f32x4){0.f, 0.f, 0.f, 0.f};

    int4 bhReg[BP], blReg[BP];

    auto loadB = [&](int k0) {
        #pragma unroll
        for (int p = 0; p < BP; p++) {
            int idx = p * 512 + tid;
            if (idx < BCH) {
                int col = idx >> 2;
                int kc = idx & 3;
                size_t o = (size_t)col * KT + k0 + kc * 8;
                bhReg[p] = *(const int4*)&Bth[o];
                blReg[p] = *(const int4*)&Btl[o];
            }
        }
    };
    auto stageB = [&]() {
        #pragma unroll
        for (int p = 0; p < BP; p++) {
            int idx = p * 512 + tid;
            if (idx < BCH) {
                int col = idx >> 2;
                int kc = idx & 3;
                *(int4*)&Bhi[col * 40 + kc * 8] = bhReg[p];
                *(int4*)&Blo[col * 40 + kc * 8] = blReg[p];
            }
        }
    };
    auto mfmaStep = [&](bf16x8 a_h, bf16x8 a_l) {
        #pragma unroll
        for (int ni = 0; ni < NI; ni++) {
            int boff = (ni * 16 + m_lane) * 40 + kgrp * 8;
            bf16x8 bh = *(const bf16x8*)&Bhi[boff];
            bf16x8 bl = *(const bf16x8*)&Blo[boff];
            acc[ni] = __builtin_amdgcn_mfma_f32_16x16x32_bf16(a_h, bh, acc[ni], 0, 0, 0);
            acc[ni] = __builtin_amdgcn_mfma_f32_16x16x32_bf16(a_l, bh, acc[ni], 0, 0, 0);
            acc[ni] = __builtin_amdgcn_mfma_f32_16x16x32_bf16(a_h, bl, acc[ni], 0, 0, 0);
        }
    };

    if constexpr (KT == 128) {
        // full A preload: 4 slices x (hi+lo) x 16 B = 128 B/thread in flight at once
        bf16x8 ahAll[4], alAll[4];
        #pragma unroll
        for (int s = 0; s < 4; s++) {
            ahAll[s] = *(const bf16x8*)&Aph[s * 32];
            alAll[s] = *(const bf16x8*)&Apl[s * 32];
        }
        loadB(0);
        #pragma unroll
        for (int ks = 0; ks < 4; ks++) {
            stageB();
            __syncthreads();
            if (ks < 3) loadB((ks + 1) * 32);
            mfmaStep(ahAll[ks], alAll[ks]);
            __syncthreads();
        }
    } else {
        bf16x8 ahN, alN, ahC, alC;
        auto loadA = [&](int k0) {
            ahN = *(const bf16x8*)&Aph[k0];
            alN = *(const bf16x8*)&Apl[k0];
        };
        loadB(0); loadA(0);
        #pragma unroll
        for (int ks = 0; ks < KSTEPS; ks++) {
            int k0 = ks * 32;
            ahC = ahN; alC = alN;
            stageB();
            __syncthreads();
            if (k0 + 32 < KT) { loadB(k0 + 32); loadA(k0 + 32); }
            mfmaStep(ahC, alC);
            __syncthreads();
        }
    }

    #pragma unroll
    for (int c = 0; c < NI / 4; c++) {
        #pragma unroll
        for (int q = 0; q < 4; q++) {
            int ni = c * 4 + q;
            float bb = 0.f;
            if (BR) bb = bias[ni * 16 + m_lane];
            #pragma unroll
            for (int reg = 0; reg < 4; reg++) {
                float v = acc[ni][reg];
                if (BR) v = fmaxf(v + bb, 0.f);
                tr[wv * 1088 + (kgrp * 4 + reg) * 68 + q * 16 + m_lane] = v;
            }
        }
        #pragma unroll
        for (int j = 0; j < 4; j++) {
            int r = (lane >> 4) + j * 4;
            int g = lane & 15;
            float4 v = *(const float4*)&tr[wv * 1088 + r * 68 + g * 4];
            int row = brow + wv * 16 + r;
            if (row < M) {
                size_t cbase = (size_t)row * BN + c * 64 + g * 4;
                if (OBF) {
                    ushort4 o;
                    o.x = f2bf_rne(v.x); o.y = f2bf_rne(v.y);
                    o.z = f2bf_rne(v.z); o.w = f2bf_rne(v.w);
                    *(ushort4*)&Cb[cbase] = o;
                } else {
                    short4 oh, ol;
                    short h, l;
                    split_bf16(v.x, h, l); oh.x = h; ol.x = l;
                    split_bf16(v.y, h, l); oh.y = h; ol.y = l;
                    split_bf16(v.z, h, l); oh.z = h; ol.z = l;
                    split_bf16(v.w, h, l); oh.w = h; ol.w = l;
                    *(short4*)&Ch[cbase] = oh;
                    *(short4*)&Cl[cbase] = ol;
                }
            }
        }
    }
}

// ---------------- aggregation: bf16 table, 8-padded CSR, precomputed edge weights ----

#define AGG_WAVES 12800
#define AGG_BLOCKS (AGG_WAVES / 4)

template<int F, bool RELU, bool BIAS, int OUTM>
__global__ void aggregate_bf16_kernel(const unsigned short* __restrict__ xb,
                                      short* __restrict__ outh,
                                      short* __restrict__ outl,
                                      float* __restrict__ outf,
                                      const float* __restrict__ dis,
                                      const int* __restrict__ starts,
                                      const int* __restrict__ ends,
                                      const unsigned short* __restrict__ csr_src,
                                      const float* __restrict__ wdis,
                                      const float* __restrict__ bias,
                                      int n) {
    int wid = (blockIdx.x * blockDim.x + threadIdx.x) >> 6;
    int lane = threadIdx.x & 63;
    constexpr int VPT = F / 64;

    for (int v = wid; v < n; v += AGG_WAVES) {
        float dv = dis[v];
        float acc[VPT];
        if constexpr (VPT == 2) {
            ushort2 sv = *(const ushort2*)&xb[(size_t)v * F + lane * 2];
            acc[0] = bf2f(sv.x) * dv;
            acc[1] = bf2f(sv.y) * dv;
        } else {
            acc[0] = bf2f(xb[(size_t)v * F + lane]) * dv;
        }
        int s = __builtin_amdgcn_readfirstlane(starts[v]);
        int e = __builtin_amdgcn_readfirstlane(ends[v]);
        for (int p = s; p < e; p += 8) {
            int4 c0 = *(const int4*)&csr_src[p];
            float4 w0 = *(const float4*)&wdis[p];
            float4 w1 = *(const float4*)&wdis[p + 4];
            int u[8];
            u[0] = (unsigned)c0.x & 0xFFFF; u[1] = (unsigned)c0.x >> 16;
            u[2] = (unsigned)c0.y & 0xFFFF; u[3] = (unsigned)c0.y >> 16;
            u[4] = (unsigned)c0.z & 0xFFFF; u[5] = (unsigned)c0.z >> 16;
            u[6] = (unsigned)c0.w & 0xFFFF; u[7] = (unsigned)c0.w >> 16;
            float w[8];
            w[0] = w0.x; w[1] = w0.y; w[2] = w0.z; w[3] = w0.w;
            w[4] = w1.x; w[5] = w1.y; w[6] = w1.z; w[7] = w1.w;
            if constexpr (VPT == 2) {
                ushort2 g[8];
                #pragma unroll
                for (int q = 0; q < 8; q++)
                    g[q] = *(const ushort2*)&xb[(size_t)u[q] * F + lane * 2];
                #pragma unroll
                for (int q = 0; q < 8; q++) {
                    acc[0] += bf2f(g[q].x) * w[q];
                    acc[1] += bf2f(g[q].y) * w[q];
                }
            } else {
                unsigned short g[8];
                #pragma unroll
                for (int q = 0; q < 8; q++)
                    g[q] = xb[(size_t)u[q] * F + lane];
                #pragma unroll
                for (int q = 0; q < 8; q++) acc[0] += bf2f(g[q]) * w[q];
            }
        }
        size_t base = (size_t)v * F + lane * VPT;
        if constexpr (OUTM == 1) {
            #pragma unroll
            for (int i = 0; i < VPT; i++) {
                float r = acc[i] * dv;
                if (BIAS) r += bias[lane * VPT + i];
                if (RELU) r = fmaxf(r, 0.f);
                outf[base + i] = r;
            }
        } else {
            if constexpr (VPT == 2) {
                float r0 = acc[0] * dv, r1 = acc[1] * dv;
                if (BIAS) { r0 += bias[lane * 2]; r1 += bias[lane * 2 + 1]; }
                if (RELU) { r0 = fmaxf(r0, 0.f); r1 = fmaxf(r1, 0.f); }
                short h0, l0, h1, l1;
                split_bf16(r0, h0, l0);
                split_bf16(r1, h1, l1);
                short2 oh; oh.x = h0; oh.y = h1;
                short2 ol; ol.x = l0; ol.y = l1;
                *(short2*)&outh[base] = oh;
                *(short2*)&outl[base] = ol;
            } else {
                float r = acc[0] * dv;
                if (BIAS) r += bias[lane];
                if (RELU) r = fmaxf(r, 0.f);
                short h, l;
                split_bf16(r, h, l);
                outh[base] = h;
                outl[base] = l;
            }
        }
    }
}

// ---------------- edge dot products: 16 lanes per edge, 4 edges per wave ----------------

__global__ void dot_kernel(const float* __restrict__ h,
                           const int* __restrict__ pos, const int* __restrict__ neg,
                           float* __restrict__ out) {
    int gw = (blockIdx.x * blockDim.x + threadIdx.x) >> 6;
    int lane = threadIdx.x & 63;
    int sub = lane >> 4;
    int pl = lane & 15;
    int e = gw * 4 + sub;
    if (e >= E_POS + E_NEG) return;
    int i0, i1;
    if (e < E_POS) { i0 = pos[e]; i1 = pos[E_POS + e]; }
    else { int t = e - E_POS; i0 = neg[t]; i1 = neg[E_NEG + t]; }
    float4 a = *(const float4*)&h[(size_t)i0 * 64 + pl * 4];
    float4 b = *(const float4*)&h[(size_t)i1 * 64 + pl * 4];
    float v = a.x * b.x + a.y * b.y + a.z * b.z + a.w * b.w;
    v += __shfl_xor(v, 1, 64);
    v += __shfl_xor(v, 2, 64);
    v += __shfl_xor(v, 4, 64);
    v += __shfl_xor(v, 8, 64);
    if (pl == 0) out[e] = v;
}

// ---------------- launch ----------------

extern "C" void kernel_launch(void* const* d_in, const int* in_sizes, int n_in,
                              void* d_out, int out_size, void* d_ws, size_t ws_size,
                              hipStream_t stream) {
    const float* x  = (const float*)d_in[0];
    const int* tei  = (const int*)d_in[1];
    const int* pos  = (const int*)d_in[2];
    const int* neg  = (const int*)d_in[3];
    const float* W1 = (const float*)d_in[4];
    const float* b1 = (const float*)d_in[5];
    const float* W2 = (const float*)d_in[6];
    const float* b2 = (const float*)d_in[7];
    const float* W3 = (const float*)d_in[8];
    const float* b3 = (const float*)d_in[9];
    float* out = (float*)d_out;

    const int* src = tei;
    const int* dst = tei + E_TRAIN;

    char* ws = (char*)d_ws;
    size_t off = 0;
    auto alloc = [&](size_t bytes) -> void* {
        void* p = ws + off;
        off = (off + bytes + 255) & ~(size_t)255;
        return p;
    };
    unsigned short* xb = (unsigned short*)alloc((size_t)N_NODES * 128 * 2);
    short* aggXh       = (short*)alloc((size_t)N_NODES * 128 * 2);
    short* aggXl       = (short*)alloc((size_t)N_NODES * 128 * 2);
    short* h1h         = (short*)alloc((size_t)N_NODES * 256 * 2);
    short* h1l         = (short*)alloc((size_t)N_NODES * 256 * 2);
    unsigned short* xw2b = (unsigned short*)alloc((size_t)N_NODES * 128 * 2);
    short* h2h         = (short*)alloc((size_t)N_NODES * 128 * 2);
    short* h2l         = (short*)alloc((size_t)N_NODES * 128 * 2);
    unsigned short* xw3b = (unsigned short*)alloc((size_t)N_NODES * 64 * 2);
    float* h3          = (float*)alloc((size_t)N_NODES * 64 * 4);
    float* dis  = (float*)alloc(N_NODES * 4);
    int* offs   = (int*)alloc(N_NODES * 4);
    int* ends   = (int*)alloc(N_NODES * 4);
    int* gcount = (int*)alloc(NBUCK * 4);
    unsigned int* temp  = (unsigned int*)alloc((size_t)NBUCK * BSTRIDE * 4);
    unsigned short* csr = (unsigned short*)alloc((size_t)NBUCK * PSTRIDE * 2);
    float* wdis         = (float*)alloc((size_t)NBUCK * PSTRIDE * 4);
    short* Wt1h = (short*)alloc((size_t)128 * 256 * 2);
    short* Wt1l = (short*)alloc((size_t)128 * 256 * 2);
    short* Wt2h = (short*)alloc((size_t)256 * 128 * 2);
    short* Wt2l = (short*)alloc((size_t)256 * 128 * 2);
    short* Wt3h = (short*)alloc((size_t)128 * 64 * 2);
    short* Wt3l = (short*)alloc((size_t)128 * 64 * 2);
    (void)ws_size; (void)n_in; (void)in_sizes; (void)out_size;

    const int n4 = N_NODES * 128 / 4;

    // CSR build + prep (fused): memset + partA/prep + partB + wdis
    hipMemsetAsync(gcount, 0, NBUCK * 4, stream);
    {
        int prep_blocks = (WTOT + n4 + 255) / 256;
        partA_prep_kernel<<<PARTA_BLOCKS + prep_blocks, 256, 0, stream>>>(
            src, dst, gcount, temp, E_TRAIN,
            W1, Wt1h, Wt1l, W2, Wt2h, Wt2l, W3, Wt3h, Wt3l, x, xb, n4);
    }
    partB_kernel<<<NBUCK, 256, 0, stream>>>(temp, gcount, dis, offs, ends, csr);
    {
        int ncsr = NBUCK * PSTRIDE;
        wdis_kernel<<<(ncsr + 255) / 256, 256, 0, stream>>>(csr, dis, wdis, ncsr);
    }

    const int GB = (N_NODES + 127) / 128;   // 391 blocks, 128 rows, 512 threads

    // layer 1 (agg-first): aggX = agg(xb) [split planes]; h1 = relu(aggX @ W1 + b1)
    aggregate_bf16_kernel<128, false, false, 0><<<AGG_BLOCKS, 256, 0, stream>>>(
        xb, aggXh, aggXl, nullptr, dis, offs, ends, csr, wdis, nullptr, N_NODES);
    gemm_fulln_kernel<128, 256, true, false><<<GB, 512, 0, stream>>>(
        aggXh, aggXl, Wt1h, Wt1l, b1, h1h, h1l, nullptr, N_NODES);

    // layer 2 (gemm-first): xw2 = h1 @ W2 (bf16 out); h2 = relu(agg + b2)
    gemm_fulln_kernel<256, 128, false, true><<<GB, 512, 0, stream>>>(
        h1h, h1l, Wt2h, Wt2l, nullptr, nullptr, nullptr, xw2b, N_NODES);
    aggregate_bf16_kernel<128, true, true, 0><<<AGG_BLOCKS, 256, 0, stream>>>(
        xw2b, h2h, h2l, nullptr, dis, offs, ends, csr, wdis, b2, N_NODES);

    // layer 3 (gemm-first): xw3 = h2 @ W3 (bf16 out); h3 = agg + b3 (fp32)
    gemm_fulln_kernel<128, 64, false, true><<<GB, 512, 0, stream>>>(
        h2h, h2l, Wt3h, Wt3l, nullptr, nullptr, nullptr, xw3b, N_NODES);
    aggregate_bf16_kernel<64, false, true, 1><<<AGG_BLOCKS, 256, 0, stream>>>(
        xw3b, nullptr, nullptr, h3, dis, offs, ends, csr, wdis, b3, N_NODES);

    // edge dots over h3 (64 features, fp32): 4 edges per wave
    const int DOT_WAVES = (E_POS + E_NEG + 3) / 4;
    dot_kernel<<<(DOT_WAVES + 3) / 4, 256, 0, stream>>>(h3, pos, neg, out);
}

// Round 6
// 298.797 us; speedup vs baseline: 1.1485x; 1.0244x over previous
//
#include <hip/hip_runtime.h>
#include <math.h>

#define N_NODES 50000
#define E_TRAIN 800000
#define E_POS 200000
#define E_NEG 200000

#define NBUCK 196        // ceil(N_NODES/256) coarse dst-buckets
#define BSTRIDE 5120     // temp slots per bucket (mean 4082, 16 sigma margin)
#define PSTRIDE 6912     // padded csr slots per bucket (raw<=5120 + 256*7 pad, mult of 8)
#define PARTA_BLOCKS 196 // ceil(E_TRAIN/4096)

// ---------------- bf16 helpers ----------------

__device__ inline void split_bf16(float f, short& h, short& l) {
    unsigned u = __float_as_uint(f);
    h = (short)(u >> 16);
    float rem = f - __uint_as_float(u & 0xFFFF0000u);
    l = (short)(__float_as_uint(rem) >> 16);
}

__device__ inline unsigned short f2bf_rne(float f) {
    unsigned u = __float_as_uint(f);
    unsigned r = u + 0x7FFFu + ((u >> 16) & 1u);
    return (unsigned short)(r >> 16);
}

__device__ inline float bf2f(unsigned short h) {
    return __uint_as_float(((unsigned)h) << 16);
}

#define WTOT (128 * 256 + 256 * 128 + 128 * 64)

// ---------------- merged: CSR partition phase A + weight/x prep ----------------

__global__ void partA_prep_kernel(
        const int* __restrict__ src, const int* __restrict__ dst,
        int* __restrict__ gcount, unsigned int* __restrict__ temp, int e,
        const float* __restrict__ W1, short* __restrict__ W1h, short* __restrict__ W1l,
        const float* __restrict__ W2, short* __restrict__ W2h, short* __restrict__ W2l,
        const float* __restrict__ W3, short* __restrict__ W3h, short* __restrict__ W3l,
        const float* __restrict__ x, unsigned short* __restrict__ xb, int n4) {
    __shared__ int hist[NBUCK];
    __shared__ int base[NBUCK];
    __shared__ int lcur[NBUCK];
    int tid = threadIdx.x;
    if (blockIdx.x < PARTA_BLOCKS) {
        for (int i = tid; i < NBUCK; i += 256) hist[i] = 0;
        __syncthreads();
        int start = blockIdx.x * 4096;
        int stop = min(start + 4096, e);
        for (int i = start + tid; i < stop; i += 256)
            atomicAdd(&hist[dst[i] >> 8], 1);
        __syncthreads();
        for (int i = tid; i < NBUCK; i += 256) {
            base[i] = atomicAdd(&gcount[i], hist[i]);
            lcur[i] = 0;
        }
        __syncthreads();
        for (int i = start + tid; i < stop; i += 256) {
            int d = dst[i];
            int b = d >> 8;
            int off = atomicAdd(&lcur[b], 1);
            temp[(size_t)b * BSTRIDE + base[b] + off] = ((unsigned)src[i] << 8) | (unsigned)(d & 255);
        }
    } else {
        int i = (blockIdx.x - PARTA_BLOCKS) * 256 + tid;
        if (i < WTOT) {
            const float* W; short *Wh, *Wl; int K, N;
            if (i < 128 * 256) { W = W1; Wh = W1h; Wl = W1l; K = 128; N = 256; }
            else if (i < 128 * 256 + 256 * 128) { i -= 128 * 256; W = W2; Wh = W2h; Wl = W2l; K = 256; N = 128; }
            else { i -= 128 * 256 + 256 * 128; W = W3; Wh = W3h; Wl = W3l; K = 128; N = 64; }
            int k = i / N, n = i - k * N;
            short h, l;
            split_bf16(W[i], h, l);
            Wh[(size_t)n * K + k] = h;
            Wl[(size_t)n * K + k] = l;
        } else {
            int j = i - WTOT;
            if (j < n4) {
                float4 v = ((const float4*)x)[j];
                ushort4 o;
                o.x = f2bf_rne(v.x); o.y = f2bf_rne(v.y);
                o.z = f2bf_rne(v.z); o.w = f2bf_rne(v.w);
                ((ushort4*)xb)[j] = o;
            }
        }
    }
}

// ---------------- phase B: per-bucket CSR with 8-padded node segments ----------------

__global__ void partB_kernel(const unsigned int* __restrict__ temp,
                             const int* __restrict__ gcount,
                             float* __restrict__ dis, int* __restrict__ offs, int* __restrict__ ends,
                             unsigned short* __restrict__ csr) {
    __shared__ int cnt[256];
    __shared__ int loc[256];
    __shared__ int cursor[256];
    int b = blockIdx.x;
    int t = threadIdx.x;
    int total = gcount[b];
    size_t tbase = (size_t)b * BSTRIDE;
    cnt[t] = 0;
    __syncthreads();
    for (int i = t; i < total; i += 256)
        atomicAdd(&cnt[temp[tbase + i] & 255], 1);
    __syncthreads();
    int c = cnt[t];
    int pc = (c + 7) & ~7;             // padded count (mult of 8)
    loc[t] = pc;
    __syncthreads();
    for (int d = 1; d < 256; d <<= 1) {
        int u = 0;
        if (t >= d) u = loc[t - d];
        __syncthreads();
        if (t >= d) loc[t] += u;
        __syncthreads();
    }
    int excl = loc[t] - pc;
    int node = b * 256 + t;
    int gstart = b * PSTRIDE + excl;   // 8-aligned (excl is sum of multiples of 8)
    if (node < N_NODES) {
        dis[node] = 1.0f / sqrtf((float)(c + 1));  // +1 self loop
        offs[node] = gstart;
        ends[node] = gstart + pc;      // padded end: agg loop is branch-free 8-batches
    }
    cursor[t] = gstart;
    __syncthreads();
    for (int i = t; i < total; i += 256) {
        unsigned v = temp[tbase + i];
        int pos = atomicAdd(&cursor[v & 255], 1);
        csr[pos] = (unsigned short)(v >> 8);
    }
    __syncthreads();
    for (int j = c; j < pc; j++)       // sentinel-fill own node's padding
        csr[gstart + j] = 0xFFFFu;
}

// edge weights: wdis[p] = dis[csr[p]] (fp32); sentinel -> src 0, weight 0.
__global__ void wdis_kernel(unsigned short* __restrict__ csr,
                            const float* __restrict__ dis,
                            float* __restrict__ wdis, int n) {
    int i = blockIdx.x * blockDim.x + threadIdx.x;
    if (i < n) {
        unsigned short s = csr[i];
        if (s == 0xFFFFu) { csr[i] = 0; wdis[i] = 0.f; }
        else wdis[i] = dis[s];
    }
}

// ---------------- MFMA GEMM: 512 threads, 128 rows x full N (proven R1 shape) ----
// A is PRE-SPLIT hi/lo bf16 planes. B in LDS via register round-trip,
// double-buffered in regs. Outputs:
//   OBF=true : single bf16 RNE plane (for gather consumers)
//   OBF=false: split hi/lo bf16 planes (for the next GEMM's A operand)

typedef short bf16x8 __attribute__((ext_vector_type(8)));
typedef float f32x4 __attribute__((ext_vector_type(4)));

template<int BN, bool BR, bool OBF>
__global__ __launch_bounds__(512) void gemm_fulln_kernel(
        const short* __restrict__ Ah, const short* __restrict__ Al,
        const short* __restrict__ Bth, const short* __restrict__ Btl,
        const float* __restrict__ bias,
        short* __restrict__ Ch, short* __restrict__ Cl,
        unsigned short* __restrict__ Cb,
        int M, int K) {
    constexpr int NI = BN / 16;
    constexpr int BCH = BN * 4;
    constexpr int BP = (BCH + 511) / 512;
    constexpr size_t BSZ = (size_t)2 * BN * 40 * 2;
    constexpr size_t TSZ = (size_t)8 * 16 * 68 * 4;
    __shared__ __align__(16) char smem[BSZ > TSZ ? BSZ : TSZ];
    short* Bhi = (short*)smem;
    short* Blo = (short*)(smem + (size_t)BN * 40 * 2);
    float* tr  = (float*)smem;

    int tid = threadIdx.x;
    int lane = tid & 63;
    int wv = tid >> 6;
    int brow = blockIdx.x * 128;
    int m_lane = lane & 15;
    int kgrp = lane >> 4;

    int myrow = brow + wv * 16 + m_lane;
    if (myrow >= M) myrow = M - 1;
    const short* Aph = &Ah[(size_t)myrow * K + kgrp * 8];
    const short* Apl = &Al[(size_t)myrow * K + kgrp * 8];

    f32x4 acc[NI];
    #pragma unroll
    for (int i = 0; i < NI; i++) acc[i] = (f32x4){0.f, 0.f, 0.f, 0.f};

    int4 bhReg[BP], blReg[BP];
    bf16x8 ahN, alN, ahC, alC;

    auto loadB = [&](int k0) {
        #pragma unroll
        for (int p = 0; p < BP; p++) {
            int idx = p * 512 + tid;
            if (idx < BCH) {
                int col = idx >> 2;
                int kc = idx & 3;
                size_t o = (size_t)col * K + k0 + kc * 8;
                bhReg[p] = *(const int4*)&Bth[o];
                blReg[p] = *(const int4*)&Btl[o];
            }
        }
    };
    auto loadA = [&](int k0) {
        ahN = *(const bf16x8*)&Aph[k0];
        alN = *(const bf16x8*)&Apl[k0];
    };

    loadB(0); loadA(0);

    for (int k0 = 0; k0 < K; k0 += 32) {
        ahC = ahN; alC = alN;
        #pragma unroll
        for (int p = 0; p < BP; p++) {
            int idx = p * 512 + tid;
            if (idx < BCH) {
                int col = idx >> 2;
                int kc = idx & 3;
                *(int4*)&Bhi[col * 40 + kc * 8] = bhReg[p];
                *(int4*)&Blo[col * 40 + kc * 8] = blReg[p];
            }
        }
        __syncthreads();

        if (k0 + 32 < K) { loadB(k0 + 32); loadA(k0 + 32); }

        #pragma unroll
        for (int ni = 0; ni < NI; ni++) {
            int boff = (ni * 16 + m_lane) * 40 + kgrp * 8;
            bf16x8 bh = *(const bf16x8*)&Bhi[boff];
            bf16x8 bl = *(const bf16x8*)&Blo[boff];
            acc[ni] = __builtin_amdgcn_mfma_f32_16x16x32_bf16(ahC, bh, acc[ni], 0, 0, 0);
            acc[ni] = __builtin_amdgcn_mfma_f32_16x16x32_bf16(alC, bh, acc[ni], 0, 0, 0);
            acc[ni] = __builtin_amdgcn_mfma_f32_16x16x32_bf16(ahC, bl, acc[ni], 0, 0, 0);
        }
        __syncthreads();
    }

    #pragma unroll
    for (int c = 0; c < NI / 4; c++) {
        #pragma unroll
        for (int q = 0; q < 4; q++) {
            int ni = c * 4 + q;
            float bb = 0.f;
            if (BR) bb = bias[ni * 16 + m_lane];
            #pragma unroll
            for (int reg = 0; reg < 4; reg++) {
                float v = acc[ni][reg];
                if (BR) v = fmaxf(v + bb, 0.f);
                tr[wv * 1088 + (kgrp * 4 + reg) * 68 + q * 16 + m_lane] = v;
            }
        }
        #pragma unroll
        for (int j = 0; j < 4; j++) {
            int r = (lane >> 4) + j * 4;
            int g = lane & 15;
            float4 v = *(const float4*)&tr[wv * 1088 + r * 68 + g * 4];
            int row = brow + wv * 16 + r;
            if (row < M) {
                if (OBF) {
                    ushort4 o;
                    o.x = f2bf_rne(v.x); o.y = f2bf_rne(v.y);
                    o.z = f2bf_rne(v.z); o.w = f2bf_rne(v.w);
                    *(ushort4*)&Cb[(size_t)row * BN + c * 64 + g * 4] = o;
                } else {
                    short4 oh, ol;
                    short h, l;
                    split_bf16(v.x, h, l); oh.x = h; ol.x = l;
                    split_bf16(v.y, h, l); oh.y = h; ol.y = l;
                    split_bf16(v.z, h, l); oh.z = h; ol.z = l;
                    split_bf16(v.w, h, l); oh.w = h; ol.w = l;
                    *(short4*)&Ch[(size_t)row * BN + c * 64 + g * 4] = oh;
                    *(short4*)&Cl[(size_t)row * BN + c * 64 + g * 4] = ol;
                }
            }
        }
    }
}

// ---------------- aggregation: bf16 table, 8-padded CSR, precomputed edge weights ----

#define AGG_WAVES 12800
#define AGG_BLOCKS (AGG_WAVES / 4)

template<int F, bool RELU, bool BIAS, int OUTM>
__global__ void aggregate_bf16_kernel(const unsigned short* __restrict__ xb,
                                      short* __restrict__ outh,
                                      short* __restrict__ outl,
                                      float* __restrict__ outf,
                                      const float* __restrict__ dis,
                                      const int* __restrict__ starts,
                                      const int* __restrict__ ends,
                                      const unsigned short* __restrict__ csr_src,
                                      const float* __restrict__ wdis,
                                      const float* __restrict__ bias,
                                      int n) {
    int wid = (blockIdx.x * blockDim.x + threadIdx.x) >> 6;
    int lane = threadIdx.x & 63;
    constexpr int VPT = F / 64;

    for (int v = wid; v < n; v += AGG_WAVES) {
        float dv = dis[v];
        float acc[VPT];
        if constexpr (VPT == 2) {
            ushort2 sv = *(const ushort2*)&xb[(size_t)v * F + lane * 2];
            acc[0] = bf2f(sv.x) * dv;
            acc[1] = bf2f(sv.y) * dv;
        } else {
            acc[0] = bf2f(xb[(size_t)v * F + lane]) * dv;
        }
        int s = __builtin_amdgcn_readfirstlane(starts[v]);
        int e = __builtin_amdgcn_readfirstlane(ends[v]);
        for (int p = s; p < e; p += 8) {
            int4 c0 = *(const int4*)&csr_src[p];
            float4 w0 = *(const float4*)&wdis[p];
            float4 w1 = *(const float4*)&wdis[p + 4];
            int u[8];
            u[0] = (unsigned)c0.x & 0xFFFF; u[1] = (unsigned)c0.x >> 16;
            u[2] = (unsigned)c0.y & 0xFFFF; u[3] = (unsigned)c0.y >> 16;
            u[4] = (unsigned)c0.z & 0xFFFF; u[5] = (unsigned)c0.z >> 16;
            u[6] = (unsigned)c0.w & 0xFFFF; u[7] = (unsigned)c0.w >> 16;
            float w[8];
            w[0] = w0.x; w[1] = w0.y; w[2] = w0.z; w[3] = w0.w;
            w[4] = w1.x; w[5] = w1.y; w[6] = w1.z; w[7] = w1.w;
            if constexpr (VPT == 2) {
                ushort2 g[8];
                #pragma unroll
                for (int q = 0; q < 8; q++)
                    g[q] = *(const ushort2*)&xb[(size_t)u[q] * F + lane * 2];
                #pragma unroll
                for (int q = 0; q < 8; q++) {
                    acc[0] += bf2f(g[q].x) * w[q];
                    acc[1] += bf2f(g[q].y) * w[q];
                }
            } else {
                unsigned short g[8];
                #pragma unroll
                for (int q = 0; q < 8; q++)
                    g[q] = xb[(size_t)u[q] * F + lane];
                #pragma unroll
                for (int q = 0; q < 8; q++) acc[0] += bf2f(g[q]) * w[q];
            }
        }
        size_t base = (size_t)v * F + lane * VPT;
        if constexpr (OUTM == 1) {
            #pragma unroll
            for (int i = 0; i < VPT; i++) {
                float r = acc[i] * dv;
                if (BIAS) r += bias[lane * VPT + i];
                if (RELU) r = fmaxf(r, 0.f);
                outf[base + i] = r;
            }
        } else {
            if constexpr (VPT == 2) {
                float r0 = acc[0] * dv, r1 = acc[1] * dv;
                if (BIAS) { r0 += bias[lane * 2]; r1 += bias[lane * 2 + 1]; }
                if (RELU) { r0 = fmaxf(r0, 0.f); r1 = fmaxf(r1, 0.f); }
                short h0, l0, h1, l1;
                split_bf16(r0, h0, l0);
                split_bf16(r1, h1, l1);
                short2 oh; oh.x = h0; oh.y = h1;
                short2 ol; ol.x = l0; ol.y = l1;
                *(short2*)&outh[base] = oh;
                *(short2*)&outl[base] = ol;
            } else {
                float r = acc[0] * dv;
                if (BIAS) r += bias[lane];
                if (RELU) r = fmaxf(r, 0.f);
                short h, l;
                split_bf16(r, h, l);
                outh[base] = h;
                outl[base] = l;
            }
        }
    }
}

// ---------------- edge dot products: 16 lanes per edge, 4 edges per wave ----------------

__global__ void dot_kernel(const float* __restrict__ h,
                           const int* __restrict__ pos, const int* __restrict__ neg,
                           float* __restrict__ out) {
    int gw = (blockIdx.x * blockDim.x + threadIdx.x) >> 6;
    int lane = threadIdx.x & 63;
    int sub = lane >> 4;
    int pl = lane & 15;
    int e = gw * 4 + sub;
    if (e >= E_POS + E_NEG) return;
    int i0, i1;
    if (e < E_POS) { i0 = pos[e]; i1 = pos[E_POS + e]; }
    else { int t = e - E_POS; i0 = neg[t]; i1 = neg[E_NEG + t]; }
    float4 a = *(const float4*)&h[(size_t)i0 * 64 + pl * 4];
    float4 b = *(const float4*)&h[(size_t)i1 * 64 + pl * 4];
    float v = a.x * b.x + a.y * b.y + a.z * b.z + a.w * b.w;
    v += __shfl_xor(v, 1, 64);
    v += __shfl_xor(v, 2, 64);
    v += __shfl_xor(v, 4, 64);
    v += __shfl_xor(v, 8, 64);
    if (pl == 0) out[e] = v;
}

// ---------------- launch ----------------

extern "C" void kernel_launch(void* const* d_in, const int* in_sizes, int n_in,
                              void* d_out, int out_size, void* d_ws, size_t ws_size,
                              hipStream_t stream) {
    const float* x  = (const float*)d_in[0];
    const int* tei  = (const int*)d_in[1];
    const int* pos  = (const int*)d_in[2];
    const int* neg  = (const int*)d_in[3];
    const float* W1 = (const float*)d_in[4];
    const float* b1 = (const float*)d_in[5];
    const float* W2 = (const float*)d_in[6];
    const float* b2 = (const float*)d_in[7];
    const float* W3 = (const float*)d_in[8];
    const float* b3 = (const float*)d_in[9];
    float* out = (float*)d_out;

    const int* src = tei;
    const int* dst = tei + E_TRAIN;

    char* ws = (char*)d_ws;
    size_t off = 0;
    auto alloc = [&](size_t bytes) -> void* {
        void* p = ws + off;
        off = (off + bytes + 255) & ~(size_t)255;
        return p;
    };
    unsigned short* xb = (unsigned short*)alloc((size_t)N_NODES * 128 * 2);
    short* aggXh       = (short*)alloc((size_t)N_NODES * 128 * 2);
    short* aggXl       = (short*)alloc((size_t)N_NODES * 128 * 2);
    short* h1h         = (short*)alloc((size_t)N_NODES * 256 * 2);
    short* h1l         = (short*)alloc((size_t)N_NODES * 256 * 2);
    unsigned short* xw2b = (unsigned short*)alloc((size_t)N_NODES * 128 * 2);
    short* h2h         = (short*)alloc((size_t)N_NODES * 128 * 2);
    short* h2l         = (short*)alloc((size_t)N_NODES * 128 * 2);
    unsigned short* xw3b = (unsigned short*)alloc((size_t)N_NODES * 64 * 2);
    float* h3          = (float*)alloc((size_t)N_NODES * 64 * 4);
    float* dis  = (float*)alloc(N_NODES * 4);
    int* offs   = (int*)alloc(N_NODES * 4);
    int* ends   = (int*)alloc(N_NODES * 4);
    int* gcount = (int*)alloc(NBUCK * 4);
    unsigned int* temp  = (unsigned int*)alloc((size_t)NBUCK * BSTRIDE * 4);
    unsigned short* csr = (unsigned short*)alloc((size_t)NBUCK * PSTRIDE * 2);
    float* wdis         = (float*)alloc((size_t)NBUCK * PSTRIDE * 4);
    short* Wt1h = (short*)alloc((size_t)128 * 256 * 2);
    short* Wt1l = (short*)alloc((size_t)128 * 256 * 2);
    short* Wt2h = (short*)alloc((size_t)256 * 128 * 2);
    short* Wt2l = (short*)alloc((size_t)256 * 128 * 2);
    short* Wt3h = (short*)alloc((size_t)128 * 64 * 2);
    short* Wt3l = (short*)alloc((size_t)128 * 64 * 2);
    (void)ws_size; (void)n_in; (void)in_sizes; (void)out_size;

    const int n4 = N_NODES * 128 / 4;

    // CSR build + prep (fused): memset + partA/prep + partB + wdis
    hipMemsetAsync(gcount, 0, NBUCK * 4, stream);
    {
        int prep_blocks = (WTOT + n4 + 255) / 256;
        partA_prep_kernel<<<PARTA_BLOCKS + prep_blocks, 256, 0, stream>>>(
            src, dst, gcount, temp, E_TRAIN,
            W1, Wt1h, Wt1l, W2, Wt2h, Wt2l, W3, Wt3h, Wt3l, x, xb, n4);
    }
    partB_kernel<<<NBUCK, 256, 0, stream>>>(temp, gcount, dis, offs, ends, csr);
    {
        int ncsr = NBUCK * PSTRIDE;
        wdis_kernel<<<(ncsr + 255) / 256, 256, 0, stream>>>(csr, dis, wdis, ncsr);
    }

    const int GB = (N_NODES + 127) / 128;

    // layer 1 (agg-first): aggX = agg(xb) [split planes]; h1 = relu(aggX @ W1 + b1) [split planes]
    aggregate_bf16_kernel<128, false, false, 0><<<AGG_BLOCKS, 256, 0, stream>>>(
        xb, aggXh, aggXl, nullptr, dis, offs, ends, csr, wdis, nullptr, N_NODES);
    gemm_fulln_kernel<256, true, false><<<GB, 512, 0, stream>>>(
        aggXh, aggXl, Wt1h, Wt1l, b1, h1h, h1l, nullptr, N_NODES, 128);

    // layer 2 (gemm-first): xw2 = h1 @ W2 (bf16 out); h2 = relu(agg + b2) [split planes]
    gemm_fulln_kernel<128, false, true><<<GB, 512, 0, stream>>>(
        h1h, h1l, Wt2h, Wt2l, nullptr, nullptr, nullptr, xw2b, N_NODES, 256);
    aggregate_bf16_kernel<128, true, true, 0><<<AGG_BLOCKS, 256, 0, stream>>>(
        xw2b, h2h, h2l, nullptr, dis, offs, ends, csr, wdis, b2, N_NODES);

    // layer 3 (gemm-first): xw3 = h2 @ W3 (bf16 out); h3 = agg + b3 (fp32)
    gemm_fulln_kernel<64, false, true><<<GB, 512, 0, stream>>>(
        h2h, h2l, Wt3h, Wt3l, nullptr, nullptr, nullptr, xw3b, N_NODES, 128);
    aggregate_bf16_kernel<64, false, true, 1><<<AGG_BLOCKS, 256, 0, stream>>>(
        xw3b, nullptr, nullptr, h3, dis, offs, ends, csr, wdis, b3, N_NODES);

    // edge dots over h3 (64 features, fp32): 4 edges per wave
    const int DOT_WAVES = (E_POS + E_NEG + 3) / 4;
    dot_kernel<<<(DOT_WAVES + 3) / 4, 256, 0, stream>>>(h3, pos, neg, out);
}

// Round 7
// 295.205 us; speedup vs baseline: 1.1625x; 1.0122x over previous
//
#include <hip/hip_runtime.h>
#include <math.h>

#define N_NODES 50000
#define E_TRAIN 800000
#define E_POS 200000
#define E_NEG 200000

#define NBUCK 196        // ceil(N_NODES/256) coarse dst-buckets
#define BSTRIDE 5120     // temp slots per bucket (mean 4082, 16 sigma margin)
#define PSTRIDE 6912     // padded csr slots per bucket (raw<=5120 + 256*7 pad, mult of 8)
#define PARTA_BLOCKS 196 // ceil(E_TRAIN/4096)

// ---------------- bf16 helpers ----------------

__device__ inline void split_bf16(float f, short& h, short& l) {
    unsigned u = __float_as_uint(f);
    h = (short)(u >> 16);
    float rem = f - __uint_as_float(u & 0xFFFF0000u);
    l = (short)(__float_as_uint(rem) >> 16);
}

__device__ inline unsigned short f2bf_rne(float f) {
    unsigned u = __float_as_uint(f);
    unsigned r = u + 0x7FFFu + ((u >> 16) & 1u);
    return (unsigned short)(r >> 16);
}

__device__ inline float bf2f(unsigned short h) {
    return __uint_as_float(((unsigned)h) << 16);
}

#define WTOT (128 * 256 + 256 * 128 + 128 * 64)

// ---------------- merged: CSR partition phase A + weight/x prep ----------------

__global__ void partA_prep_kernel(
        const int* __restrict__ src, const int* __restrict__ dst,
        int* __restrict__ gcount, unsigned int* __restrict__ temp, int e,
        const float* __restrict__ W1, short* __restrict__ W1h, short* __restrict__ W1l,
        const float* __restrict__ W2, short* __restrict__ W2h, short* __restrict__ W2l,
        const float* __restrict__ W3, short* __restrict__ W3h, short* __restrict__ W3l,
        const float* __restrict__ x, unsigned short* __restrict__ xb, int n4) {
    __shared__ int hist[NBUCK];
    __shared__ int base[NBUCK];
    __shared__ int lcur[NBUCK];
    int tid = threadIdx.x;
    if (blockIdx.x < PARTA_BLOCKS) {
        for (int i = tid; i < NBUCK; i += 256) hist[i] = 0;
        __syncthreads();
        int start = blockIdx.x * 4096;
        int stop = min(start + 4096, e);
        for (int i = start + tid; i < stop; i += 256)
            atomicAdd(&hist[dst[i] >> 8], 1);
        __syncthreads();
        for (int i = tid; i < NBUCK; i += 256) {
            base[i] = atomicAdd(&gcount[i], hist[i]);
            lcur[i] = 0;
        }
        __syncthreads();
        for (int i = start + tid; i < stop; i += 256) {
            int d = dst[i];
            int b = d >> 8;
            int off = atomicAdd(&lcur[b], 1);
            temp[(size_t)b * BSTRIDE + base[b] + off] = ((unsigned)src[i] << 8) | (unsigned)(d & 255);
        }
    } else {
        int i = (blockIdx.x - PARTA_BLOCKS) * 256 + tid;
        if (i < WTOT) {
            const float* W; short *Wh, *Wl; int K, N;
            if (i < 128 * 256) { W = W1; Wh = W1h; Wl = W1l; K = 128; N = 256; }
            else if (i < 128 * 256 + 256 * 128) { i -= 128 * 256; W = W2; Wh = W2h; Wl = W2l; K = 256; N = 128; }
            else { i -= 128 * 256 + 256 * 128; W = W3; Wh = W3h; Wl = W3l; K = 128; N = 64; }
            int k = i / N, n = i - k * N;
            short h, l;
            split_bf16(W[i], h, l);
            Wh[(size_t)n * K + k] = h;
            Wl[(size_t)n * K + k] = l;
        } else {
            int j = i - WTOT;
            if (j < n4) {
                float4 v = ((const float4*)x)[j];
                ushort4 o;
                o.x = f2bf_rne(v.x); o.y = f2bf_rne(v.y);
                o.z = f2bf_rne(v.z); o.w = f2bf_rne(v.w);
                ((ushort4*)xb)[j] = o;
            }
        }
    }
}

// ---------------- phase B: per-bucket CSR with 8-padded node segments ----------------

__global__ void partB_kernel(const unsigned int* __restrict__ temp,
                             const int* __restrict__ gcount,
                             float* __restrict__ dis, int* __restrict__ offs, int* __restrict__ ends,
                             unsigned short* __restrict__ csr) {
    __shared__ int cnt[256];
    __shared__ int loc[256];
    __shared__ int cursor[256];
    int b = blockIdx.x;
    int t = threadIdx.x;
    int total = gcount[b];
    size_t tbase = (size_t)b * BSTRIDE;
    cnt[t] = 0;
    __syncthreads();
    for (int i = t; i < total; i += 256)
        atomicAdd(&cnt[temp[tbase + i] & 255], 1);
    __syncthreads();
    int c = cnt[t];
    int pc = (c + 7) & ~7;             // padded count (mult of 8)
    loc[t] = pc;
    __syncthreads();
    for (int d = 1; d < 256; d <<= 1) {
        int u = 0;
        if (t >= d) u = loc[t - d];
        __syncthreads();
        if (t >= d) loc[t] += u;
        __syncthreads();
    }
    int excl = loc[t] - pc;
    int node = b * 256 + t;
    int gstart = b * PSTRIDE + excl;   // 8-aligned (excl is sum of multiples of 8)
    if (node < N_NODES) {
        dis[node] = 1.0f / sqrtf((float)(c + 1));  // +1 self loop
        offs[node] = gstart;
        ends[node] = gstart + pc;      // padded end: agg loop is branch-free 8-batches
    }
    cursor[t] = gstart;
    __syncthreads();
    for (int i = t; i < total; i += 256) {
        unsigned v = temp[tbase + i];
        int pos = atomicAdd(&cursor[v & 255], 1);
        csr[pos] = (unsigned short)(v >> 8);
    }
    __syncthreads();
    for (int j = c; j < pc; j++)       // sentinel-fill own node's padding
        csr[gstart + j] = 0xFFFFu;
}

// edge weights: wdis[p] = dis[csr[p]] (fp32); sentinel -> src 0, weight 0.
__global__ void wdis_kernel(unsigned short* __restrict__ csr,
                            const float* __restrict__ dis,
                            float* __restrict__ wdis, int n) {
    int i = blockIdx.x * blockDim.x + threadIdx.x;
    if (i < n) {
        unsigned short s = csr[i];
        if (s == 0xFFFFu) { csr[i] = 0; wdis[i] = 0.f; }
        else wdis[i] = dis[s];
    }
}

// ---------------- MFMA GEMM: 512 threads, 128 rows x full N (proven R1 shape, FROZEN) ----

typedef short bf16x8 __attribute__((ext_vector_type(8)));
typedef float f32x4 __attribute__((ext_vector_type(4)));

template<int BN, bool BR, bool OBF>
__global__ __launch_bounds__(512) void gemm_fulln_kernel(
        const short* __restrict__ Ah, const short* __restrict__ Al,
        const short* __restrict__ Bth, const short* __restrict__ Btl,
        const float* __restrict__ bias,
        short* __restrict__ Ch, short* __restrict__ Cl,
        unsigned short* __restrict__ Cb,
        int M, int K) {
    constexpr int NI = BN / 16;
    constexpr int BCH = BN * 4;
    constexpr int BP = (BCH + 511) / 512;
    constexpr size_t BSZ = (size_t)2 * BN * 40 * 2;
    constexpr size_t TSZ = (size_t)8 * 16 * 68 * 4;
    __shared__ __align__(16) char smem[BSZ > TSZ ? BSZ : TSZ];
    short* Bhi = (short*)smem;
    short* Blo = (short*)(smem + (size_t)BN * 40 * 2);
    float* tr  = (float*)smem;

    int tid = threadIdx.x;
    int lane = tid & 63;
    int wv = tid >> 6;
    int brow = blockIdx.x * 128;
    int m_lane = lane & 15;
    int kgrp = lane >> 4;

    int myrow = brow + wv * 16 + m_lane;
    if (myrow >= M) myrow = M - 1;
    const short* Aph = &Ah[(size_t)myrow * K + kgrp * 8];
    const short* Apl = &Al[(size_t)myrow * K + kgrp * 8];

    f32x4 acc[NI];
    #pragma unroll
    for (int i = 0; i < NI; i++) acc[i] = (f32x4){0.f, 0.f, 0.f, 0.f};

    int4 bhReg[BP], blReg[BP];
    bf16x8 ahN, alN, ahC, alC;

    auto loadB = [&](int k0) {
        #pragma unroll
        for (int p = 0; p < BP; p++) {
            int idx = p * 512 + tid;
            if (idx < BCH) {
                int col = idx >> 2;
                int kc = idx & 3;
                size_t o = (size_t)col * K + k0 + kc * 8;
                bhReg[p] = *(const int4*)&Bth[o];
                blReg[p] = *(const int4*)&Btl[o];
            }
        }
    };
    auto loadA = [&](int k0) {
        ahN = *(const bf16x8*)&Aph[k0];
        alN = *(const bf16x8*)&Apl[k0];
    };

    loadB(0); loadA(0);

    for (int k0 = 0; k0 < K; k0 += 32) {
        ahC = ahN; alC = alN;
        #pragma unroll
        for (int p = 0; p < BP; p++) {
            int idx = p * 512 + tid;
            if (idx < BCH) {
                int col = idx >> 2;
                int kc = idx & 3;
                *(int4*)&Bhi[col * 40 + kc * 8] = bhReg[p];
                *(int4*)&Blo[col * 40 + kc * 8] = blReg[p];
            }
        }
        __syncthreads();

        if (k0 + 32 < K) { loadB(k0 + 32); loadA(k0 + 32); }

        #pragma unroll
        for (int ni = 0; ni < NI; ni++) {
            int boff = (ni * 16 + m_lane) * 40 + kgrp * 8;
            bf16x8 bh = *(const bf16x8*)&Bhi[boff];
            bf16x8 bl = *(const bf16x8*)&Blo[boff];
            acc[ni] = __builtin_amdgcn_mfma_f32_16x16x32_bf16(ahC, bh, acc[ni], 0, 0, 0);
            acc[ni] = __builtin_amdgcn_mfma_f32_16x16x32_bf16(alC, bh, acc[ni], 0, 0, 0);
            acc[ni] = __builtin_amdgcn_mfma_f32_16x16x32_bf16(ahC, bl, acc[ni], 0, 0, 0);
        }
        __syncthreads();
    }

    #pragma unroll
    for (int c = 0; c < NI / 4; c++) {
        #pragma unroll
        for (int q = 0; q < 4; q++) {
            int ni = c * 4 + q;
            float bb = 0.f;
            if (BR) bb = bias[ni * 16 + m_lane];
            #pragma unroll
            for (int reg = 0; reg < 4; reg++) {
                float v = acc[ni][reg];
                if (BR) v = fmaxf(v + bb, 0.f);
                tr[wv * 1088 + (kgrp * 4 + reg) * 68 + q * 16 + m_lane] = v;
            }
        }
        #pragma unroll
        for (int j = 0; j < 4; j++) {
            int r = (lane >> 4) + j * 4;
            int g = lane & 15;
            float4 v = *(const float4*)&tr[wv * 1088 + r * 68 + g * 4];
            int row = brow + wv * 16 + r;
            if (row < M) {
                if (OBF) {
                    ushort4 o;
                    o.x = f2bf_rne(v.x); o.y = f2bf_rne(v.y);
                    o.z = f2bf_rne(v.z); o.w = f2bf_rne(v.w);
                    *(ushort4*)&Cb[(size_t)row * BN + c * 64 + g * 4] = o;
                } else {
                    short4 oh, ol;
                    short h, l;
                    split_bf16(v.x, h, l); oh.x = h; ol.x = l;
                    split_bf16(v.y, h, l); oh.y = h; ol.y = l;
                    split_bf16(v.z, h, l); oh.z = h; ol.z = l;
                    split_bf16(v.w, h, l); oh.w = h; ol.w = l;
                    *(short4*)&Ch[(size_t)row * BN + c * 64 + g * 4] = oh;
                    *(short4*)&Cl[(size_t)row * BN + c * 64 + g * 4] = ol;
                }
            }
        }
    }
}

// ---------------- aggregation: DUAL-NODE interleave for 2x gather MLP ----------------
// Each wave processes nodes v and v+AGG_WAVES concurrently: two independent
// csr->gather->fma dependency chains in flight (~2x outstanding L3 gathers).
// Per-node batch order and accumulation order unchanged -> bit-identical output.

#define AGG_WAVES 12800
#define AGG_BLOCKS (AGG_WAVES / 4)

template<int F, bool RELU, bool BIAS, int OUTM>
__global__ void aggregate_bf16_kernel(const unsigned short* __restrict__ xb,
                                      short* __restrict__ outh,
                                      short* __restrict__ outl,
                                      float* __restrict__ outf,
                                      const float* __restrict__ dis,
                                      const int* __restrict__ starts,
                                      const int* __restrict__ ends,
                                      const unsigned short* __restrict__ csr_src,
                                      const float* __restrict__ wdis,
                                      const float* __restrict__ bias,
                                      int n) {
    int wid = (blockIdx.x * blockDim.x + threadIdx.x) >> 6;
    int lane = threadIdx.x & 63;
    constexpr int VPT = F / 64;

    auto batch = [&](int p, float (&acc)[VPT]) {
        int4 c0 = *(const int4*)&csr_src[p];
        float4 w0 = *(const float4*)&wdis[p];
        float4 w1 = *(const float4*)&wdis[p + 4];
        int u[8];
        u[0] = (unsigned)c0.x & 0xFFFF; u[1] = (unsigned)c0.x >> 16;
        u[2] = (unsigned)c0.y & 0xFFFF; u[3] = (unsigned)c0.y >> 16;
        u[4] = (unsigned)c0.z & 0xFFFF; u[5] = (unsigned)c0.z >> 16;
        u[6] = (unsigned)c0.w & 0xFFFF; u[7] = (unsigned)c0.w >> 16;
        float w[8];
        w[0] = w0.x; w[1] = w0.y; w[2] = w0.z; w[3] = w0.w;
        w[4] = w1.x; w[5] = w1.y; w[6] = w1.z; w[7] = w1.w;
        if constexpr (VPT == 2) {
            ushort2 g[8];
            #pragma unroll
            for (int q = 0; q < 8; q++)
                g[q] = *(const ushort2*)&xb[(size_t)u[q] * F + lane * 2];
            #pragma unroll
            for (int q = 0; q < 8; q++) {
                acc[0] += bf2f(g[q].x) * w[q];
                acc[1] += bf2f(g[q].y) * w[q];
            }
        } else {
            unsigned short g[8];
            #pragma unroll
            for (int q = 0; q < 8; q++)
                g[q] = xb[(size_t)u[q] * F + lane];
            #pragma unroll
            for (int q = 0; q < 8; q++) acc[0] += bf2f(g[q]) * w[q];
        }
    };

    auto store = [&](int v, float dv, float (&acc)[VPT]) {
        size_t base = (size_t)v * F + lane * VPT;
        if constexpr (OUTM == 1) {
            #pragma unroll
            for (int i = 0; i < VPT; i++) {
                float r = acc[i] * dv;
                if (BIAS) r += bias[lane * VPT + i];
                if (RELU) r = fmaxf(r, 0.f);
                outf[base + i] = r;
            }
        } else {
            if constexpr (VPT == 2) {
                float r0 = acc[0] * dv, r1 = acc[1] * dv;
                if (BIAS) { r0 += bias[lane * 2]; r1 += bias[lane * 2 + 1]; }
                if (RELU) { r0 = fmaxf(r0, 0.f); r1 = fmaxf(r1, 0.f); }
                short h0, l0, h1, l1;
                split_bf16(r0, h0, l0);
                split_bf16(r1, h1, l1);
                short2 oh; oh.x = h0; oh.y = h1;
                short2 ol; ol.x = l0; ol.y = l1;
                *(short2*)&outh[base] = oh;
                *(short2*)&outl[base] = ol;
            } else {
                float r = acc[0] * dv;
                if (BIAS) r += bias[lane];
                if (RELU) r = fmaxf(r, 0.f);
                short h, l;
                split_bf16(r, h, l);
                outh[base] = h;
                outl[base] = l;
            }
        }
    };

    for (int v0 = wid; v0 < n; v0 += 2 * AGG_WAVES) {
        int v1 = v0 + AGG_WAVES;
        bool has1 = (v1 < n);

        float dv0 = dis[v0];
        float dv1 = has1 ? dis[v1] : 1.0f;
        float a0[VPT], a1[VPT];
        if constexpr (VPT == 2) {
            ushort2 sv0 = *(const ushort2*)&xb[(size_t)v0 * F + lane * 2];
            a0[0] = bf2f(sv0.x) * dv0;
            a0[1] = bf2f(sv0.y) * dv0;
            if (has1) {
                ushort2 sv1 = *(const ushort2*)&xb[(size_t)v1 * F + lane * 2];
                a1[0] = bf2f(sv1.x) * dv1;
                a1[1] = bf2f(sv1.y) * dv1;
            } else { a1[0] = 0.f; a1[1] = 0.f; }
        } else {
            a0[0] = bf2f(xb[(size_t)v0 * F + lane]) * dv0;
            if (has1) a1[0] = bf2f(xb[(size_t)v1 * F + lane]) * dv1;
            else a1[0] = 0.f;
        }

        int s0 = __builtin_amdgcn_readfirstlane(starts[v0]);
        int e0 = __builtin_amdgcn_readfirstlane(ends[v0]);
        int s1 = 0, e1 = 0;
        if (has1) {
            s1 = __builtin_amdgcn_readfirstlane(starts[v1]);
            e1 = __builtin_amdgcn_readfirstlane(ends[v1]);
        }

        int p0 = s0, p1 = s1;
        // main: both contexts active -> two independent gather streams in flight
        while (p0 < e0 && p1 < e1) {
            batch(p0, a0);
            batch(p1, a1);
            p0 += 8; p1 += 8;
        }
        for (; p0 < e0; p0 += 8) batch(p0, a0);
        for (; p1 < e1; p1 += 8) batch(p1, a1);

        store(v0, dv0, a0);
        if (has1) store(v1, dv1, a1);
    }
}

// ---------------- edge dot products: 16 lanes per edge, 4 edges per wave ----------------

__global__ void dot_kernel(const float* __restrict__ h,
                           const int* __restrict__ pos, const int* __restrict__ neg,
                           float* __restrict__ out) {
    int gw = (blockIdx.x * blockDim.x + threadIdx.x) >> 6;
    int lane = threadIdx.x & 63;
    int sub = lane >> 4;
    int pl = lane & 15;
    int e = gw * 4 + sub;
    if (e >= E_POS + E_NEG) return;
    int i0, i1;
    if (e < E_POS) { i0 = pos[e]; i1 = pos[E_POS + e]; }
    else { int t = e - E_POS; i0 = neg[t]; i1 = neg[E_NEG + t]; }
    float4 a = *(const float4*)&h[(size_t)i0 * 64 + pl * 4];
    float4 b = *(const float4*)&h[(size_t)i1 * 64 + pl * 4];
    float v = a.x * b.x + a.y * b.y + a.z * b.z + a.w * b.w;
    v += __shfl_xor(v, 1, 64);
    v += __shfl_xor(v, 2, 64);
    v += __shfl_xor(v, 4, 64);
    v += __shfl_xor(v, 8, 64);
    if (pl == 0) out[e] = v;
}

// ---------------- launch ----------------

extern "C" void kernel_launch(void* const* d_in, const int* in_sizes, int n_in,
                              void* d_out, int out_size, void* d_ws, size_t ws_size,
                              hipStream_t stream) {
    const float* x  = (const float*)d_in[0];
    const int* tei  = (const int*)d_in[1];
    const int* pos  = (const int*)d_in[2];
    const int* neg  = (const int*)d_in[3];
    const float* W1 = (const float*)d_in[4];
    const float* b1 = (const float*)d_in[5];
    const float* W2 = (const float*)d_in[6];
    const float* b2 = (const float*)d_in[7];
    const float* W3 = (const float*)d_in[8];
    const float* b3 = (const float*)d_in[9];
    float* out = (float*)d_out;

    const int* src = tei;
    const int* dst = tei + E_TRAIN;

    char* ws = (char*)d_ws;
    size_t off = 0;
    auto alloc = [&](size_t bytes) -> void* {
        void* p = ws + off;
        off = (off + bytes + 255) & ~(size_t)255;
        return p;
    };
    unsigned short* xb = (unsigned short*)alloc((size_t)N_NODES * 128 * 2);
    short* aggXh       = (short*)alloc((size_t)N_NODES * 128 * 2);
    short* aggXl       = (short*)alloc((size_t)N_NODES * 128 * 2);
    short* h1h         = (short*)alloc((size_t)N_NODES * 256 * 2);
    short* h1l         = (short*)alloc((size_t)N_NODES * 256 * 2);
    unsigned short* xw2b = (unsigned short*)alloc((size_t)N_NODES * 128 * 2);
    short* h2h         = (short*)alloc((size_t)N_NODES * 128 * 2);
    short* h2l         = (short*)alloc((size_t)N_NODES * 128 * 2);
    unsigned short* xw3b = (unsigned short*)alloc((size_t)N_NODES * 64 * 2);
    float* h3          = (float*)alloc((size_t)N_NODES * 64 * 4);
    float* dis  = (float*)alloc(N_NODES * 4);
    int* offs   = (int*)alloc(N_NODES * 4);
    int* ends   = (int*)alloc(N_NODES * 4);
    int* gcount = (int*)alloc(NBUCK * 4);
    unsigned int* temp  = (unsigned int*)alloc((size_t)NBUCK * BSTRIDE * 4);
    unsigned short* csr = (unsigned short*)alloc((size_t)NBUCK * PSTRIDE * 2);
    float* wdis         = (float*)alloc((size_t)NBUCK * PSTRIDE * 4);
    short* Wt1h = (short*)alloc((size_t)128 * 256 * 2);
    short* Wt1l = (short*)alloc((size_t)128 * 256 * 2);
    short* Wt2h = (short*)alloc((size_t)256 * 128 * 2);
    short* Wt2l = (short*)alloc((size_t)256 * 128 * 2);
    short* Wt3h = (short*)alloc((size_t)128 * 64 * 2);
    short* Wt3l = (short*)alloc((size_t)128 * 64 * 2);
    (void)ws_size; (void)n_in; (void)in_sizes; (void)out_size;

    const int n4 = N_NODES * 128 / 4;

    // CSR build + prep (fused): memset + partA/prep + partB + wdis
    hipMemsetAsync(gcount, 0, NBUCK * 4, stream);
    {
        int prep_blocks = (WTOT + n4 + 255) / 256;
        partA_prep_kernel<<<PARTA_BLOCKS + prep_blocks, 256, 0, stream>>>(
            src, dst, gcount, temp, E_TRAIN,
            W1, Wt1h, Wt1l, W2, Wt2h, Wt2l, W3, Wt3h, Wt3l, x, xb, n4);
    }
    partB_kernel<<<NBUCK, 256, 0, stream>>>(temp, gcount, dis, offs, ends, csr);
    {
        int ncsr = NBUCK * PSTRIDE;
        wdis_kernel<<<(ncsr + 255) / 256, 256, 0, stream>>>(csr, dis, wdis, ncsr);
    }

    const int GB = (N_NODES + 127) / 128;

    // layer 1 (agg-first): aggX = agg(xb) [split planes]; h1 = relu(aggX @ W1 + b1) [split planes]
    aggregate_bf16_kernel<128, false, false, 0><<<AGG_BLOCKS, 256, 0, stream>>>(
        xb, aggXh, aggXl, nullptr, dis, offs, ends, csr, wdis, nullptr, N_NODES);
    gemm_fulln_kernel<256, true, false><<<GB, 512, 0, stream>>>(
        aggXh, aggXl, Wt1h, Wt1l, b1, h1h, h1l, nullptr, N_NODES, 128);

    // layer 2 (gemm-first): xw2 = h1 @ W2 (bf16 out); h2 = relu(agg + b2) [split planes]
    gemm_fulln_kernel<128, false, true><<<GB, 512, 0, stream>>>(
        h1h, h1l, Wt2h, Wt2l, nullptr, nullptr, nullptr, xw2b, N_NODES, 256);
    aggregate_bf16_kernel<128, true, true, 0><<<AGG_BLOCKS, 256, 0, stream>>>(
        xw2b, h2h, h2l, nullptr, dis, offs, ends, csr, wdis, b2, N_NODES);

    // layer 3 (gemm-first): xw3 = h2 @ W3 (bf16 out); h3 = agg + b3 (fp32)
    gemm_fulln_kernel<64, false, true><<<GB, 512, 0, stream>>>(
        h2h, h2l, Wt3h, Wt3l, nullptr, nullptr, nullptr, xw3b, N_NODES, 128);
    aggregate_bf16_kernel<64, false, true, 1><<<AGG_BLOCKS, 256, 0, stream>>>(
        xw3b, nullptr, nullptr, h3, dis, offs, ends, csr, wdis, b3, N_NODES);

    // edge dots over h3 (64 features, fp32): 4 edges per wave
    const int DOT_WAVES = (E_POS + E_NEG + 3) / 4;
    dot_kernel<<<(DOT_WAVES + 3) / 4, 256, 0, stream>>>(h3, pos, neg, out);
}